// Round 1
// baseline (40764.734 us; speedup 1.0000x reference)
//
#include <hip/hip_runtime.h>
#include <hip/hip_cooperative_groups.h>
#include <math.h>

namespace cg = cooperative_groups;

#define BATCH 32
#define TLEN  512
#define HID   1024
#define G2    2048   // 2*H

// ---------------------------------------------------------------------------
// Projection GEMM: Cw[t][b][n] = sum_k A[m][k] * W[n][k],  m = b*TLEN + t
// A: [M,K] row-major (M = 16384), W: [N,K] row-major (N = 2048)
// Output permuted to [T][B][2H] so the recurrence reads contiguous slabs.
// ---------------------------------------------------------------------------
__global__ __launch_bounds__(256)
void proj_gemm(const float* __restrict__ A, const float* __restrict__ W,
               float* __restrict__ Cw, int K) {
    __shared__ float As[16][132];
    __shared__ float Bs[16][132];

    const int bm = blockIdx.x;          // M/128 tiles
    const int bn = blockIdx.y;          // N/128 tiles
    const int tid = threadIdx.x;
    const int tx = tid & 15;            // n micro
    const int ty = tid >> 4;            // m micro

    const int row0 = bm * 128;
    const int col0 = bn * 128;

    float acc[8][8];
    #pragma unroll
    for (int i = 0; i < 8; ++i)
        #pragma unroll
        for (int j = 0; j < 8; ++j) acc[i][j] = 0.f;

    for (int k0 = 0; k0 < K; k0 += 16) {
        // stage A and W tiles (128 rows x 16 k) transposed into LDS
        #pragma unroll
        for (int i = 0; i < 2; ++i) {
            int f = tid + i * 256;            // float4 id 0..511
            int r = f >> 2;                   // row 0..127
            int c = (f & 3) * 4;              // k 0..12
            float4 va = *(const float4*)&A[(size_t)(row0 + r) * K + k0 + c];
            As[c + 0][r] = va.x; As[c + 1][r] = va.y;
            As[c + 2][r] = va.z; As[c + 3][r] = va.w;
            float4 vb = *(const float4*)&W[(size_t)(col0 + r) * K + k0 + c];
            Bs[c + 0][r] = vb.x; Bs[c + 1][r] = vb.y;
            Bs[c + 2][r] = vb.z; Bs[c + 3][r] = vb.w;
        }
        __syncthreads();

        #pragma unroll
        for (int kk = 0; kk < 16; ++kk) {
            float a[8], b[8];
            #pragma unroll
            for (int i = 0; i < 8; ++i) a[i] = As[kk][ty * 8 + i];
            #pragma unroll
            for (int j = 0; j < 8; ++j) b[j] = Bs[kk][tx * 8 + j];
            #pragma unroll
            for (int i = 0; i < 8; ++i)
                #pragma unroll
                for (int j = 0; j < 8; ++j)
                    acc[i][j] += a[i] * b[j];
        }
        __syncthreads();
    }

    // write out permuted: m -> (t = m % T, b = m / T)
    #pragma unroll
    for (int i = 0; i < 8; ++i) {
        int m = row0 + ty * 8 + i;
        int t = m & (TLEN - 1);
        int bb = m >> 9;
        float* dst = &Cw[((size_t)t * BATCH + bb) * G2 + col0 + tx * 8];
        #pragma unroll
        for (int j = 0; j < 8; ++j) dst[j] = acc[i][j];
    }
}

// ---------------------------------------------------------------------------
// Recurrence: persistent cooperative kernel, one grid.sync per timestep.
// 256 WGs x 512 threads. WG wg owns j in [wg*4, wg*4+4); keeps the 8 needed
// U rows (a-rows j, z-rows H+j) resident in LDS for all 512 steps.
// Thread layout: p = tid&127 -> (b = p>>2, jl = p&3); q = tid>>7 = K-quarter.
// h ping-pongs between two global buffers (race-free vs. other WGs' reads).
// ---------------------------------------------------------------------------
#define NWG 256
#define JPW 4

__global__ __launch_bounds__(512, 1)
void ligru_rec(const float* __restrict__ w,    // [T][B][2H]
               const float* __restrict__ U,    // [2H][H]
               float* h0w, float* h1w,         // [B][H] ping-pong
               float* __restrict__ out,        // [B][T][H]
               float* __restrict__ hlast) {    // [B][H]
    cg::grid_group grid = cg::this_grid();

    __shared__ float Ua[JPW][HID + 4];
    __shared__ float Uz[JPW][HID + 4];
    __shared__ float red_a[3][128];
    __shared__ float red_z[3][128];

    const int wg  = blockIdx.x;
    const int tid = threadIdx.x;
    const int j0  = wg * JPW;

    // stage this WG's U slice into LDS (stays for the whole kernel)
    for (int f = tid; f < JPW * (HID / 4); f += 512) {
        int r = f / (HID / 4);
        int c = (f % (HID / 4)) * 4;
        *(float4*)&Ua[r][c] = *(const float4*)&U[(size_t)(j0 + r) * HID + c];
        *(float4*)&Uz[r][c] = *(const float4*)&U[(size_t)(HID + j0 + r) * HID + c];
    }
    // zero initial h
    {
        int gid = wg * 512 + tid;
        if (gid < BATCH * HID) h0w[gid] = 0.f;
    }
    __syncthreads();
    grid.sync();

    const int p  = tid & 127;
    const int q  = tid >> 7;        // K-quarter 0..3
    const int b  = p >> 2;          // 0..31
    const int jl = p & 3;           // 0..3
    const int jg = j0 + jl;
    const int k0 = q * 256;

    float* hcur = h0w;
    float* hnxt = h1w;

    for (int t = 0; t < TLEN; ++t) {
        const float* hb = hcur + (size_t)b * HID + k0;
        const float* ua = &Ua[jl][k0];
        const float* uz = &Uz[jl][k0];
        float sa0 = 0.f, sa1 = 0.f, sz0 = 0.f, sz1 = 0.f;
        #pragma unroll 8
        for (int k = 0; k < 256; k += 8) {
            float4 hv0 = *(const float4*)&hb[k];
            float4 hv1 = *(const float4*)&hb[k + 4];
            float4 av0 = *(const float4*)&ua[k];
            float4 av1 = *(const float4*)&ua[k + 4];
            float4 zv0 = *(const float4*)&uz[k];
            float4 zv1 = *(const float4*)&uz[k + 4];
            sa0 += hv0.x * av0.x + hv0.y * av0.y + hv0.z * av0.z + hv0.w * av0.w;
            sa1 += hv1.x * av1.x + hv1.y * av1.y + hv1.z * av1.z + hv1.w * av1.w;
            sz0 += hv0.x * zv0.x + hv0.y * zv0.y + hv0.z * zv0.z + hv0.w * zv0.w;
            sz1 += hv1.x * zv1.x + hv1.y * zv1.y + hv1.z * zv1.z + hv1.w * zv1.w;
        }
        float sa = sa0 + sa1;
        float sz = sz0 + sz1;

        if (q) { red_a[q - 1][p] = sa; red_z[q - 1][p] = sz; }
        __syncthreads();
        if (!q) {
            sa += red_a[0][p] + red_a[1][p] + red_a[2][p];
            sz += red_z[0][p] + red_z[1][p] + red_z[2][p];
            const float* wt = &w[((size_t)t * BATCH + b) * G2];
            float at = wt[jg] + sa;
            float zt = wt[HID + jg] + sz;
            zt = 1.f / (1.f + expf(-zt));
            float hc = tanhf(at);
            float hold = hcur[(size_t)b * HID + jg];
            float hnew = zt * hold + (1.f - zt) * hc;
            out[((size_t)b * TLEN + t) * HID + jg] = hnew;
            hnxt[(size_t)b * HID + jg] = hnew;
            if (t == TLEN - 1) hlast[(size_t)b * HID + jg] = hnew;
        }
        grid.sync();
        float* tmp = hcur; hcur = hnxt; hnxt = tmp;
    }
}

// ---------------------------------------------------------------------------
extern "C" void kernel_launch(void* const* d_in, const int* in_sizes, int n_in,
                              void* d_out, int out_size, void* d_ws, size_t ws_size,
                              hipStream_t stream) {
    (void)in_sizes; (void)n_in; (void)out_size; (void)ws_size;

    const float* x  = (const float*)d_in[0];
    const float* W0 = (const float*)d_in[1];
    const float* U0 = (const float*)d_in[2];
    const float* W1 = (const float*)d_in[3];
    const float* U1 = (const float*)d_in[4];

    float* out    = (float*)d_out;                              // [B,T,H]
    float* hstack = out + (size_t)BATCH * TLEN * HID;           // [2,B,H]

    float* h0   = (float*)d_ws;                                 // [B,H]
    float* h1   = h0 + BATCH * HID;                             // [B,H]
    float* wbuf = h1 + BATCH * HID;                             // [T][B][2H]

    dim3 gg(16384 / 128, 2048 / 128);

    // ---- layer 0 ----
    proj_gemm<<<gg, 256, 0, stream>>>(x, W0, wbuf, 512);
    {
        const float* wb = wbuf; const float* Up = U0;
        float* a = h0; float* bptr = h1; float* o = out; float* hl = hstack;
        void* args[] = {&wb, &Up, &a, &bptr, &o, &hl};
        hipLaunchCooperativeKernel((void*)ligru_rec, dim3(NWG), dim3(512),
                                   args, 0, stream);
    }

    // ---- layer 1 ---- (reads layer-0 output staged in d_out, then overwrites it)
    proj_gemm<<<gg, 256, 0, stream>>>(out, W1, wbuf, 1024);
    {
        const float* wb = wbuf; const float* Up = U1;
        float* a = h0; float* bptr = h1; float* o = out;
        float* hl = hstack + BATCH * HID;
        void* args[] = {&wb, &Up, &a, &bptr, &o, &hl};
        hipLaunchCooperativeKernel((void*)ligru_rec, dim3(NWG), dim3(512),
                                   args, 0, stream);
    }
}

// Round 2
// 29044.922 us; speedup vs baseline: 1.4035x; 1.4035x over previous
//
#include <hip/hip_runtime.h>
#include <hip/hip_cooperative_groups.h>
#include <math.h>

#define BATCH 32
#define TLEN  512
#define HID   1024
#define G2    2048   // 2*H

// ---------------------------------------------------------------------------
// Projection GEMM: Cw[t][b][n] = sum_k A[m][k] * W[n][k],  m = b*TLEN + t
// A: [M,K] row-major (M = 16384), W: [N,K] row-major (N = 2048)
// Output permuted to [T][B][2H] so the recurrence reads contiguous slabs.
// ---------------------------------------------------------------------------
__global__ __launch_bounds__(256)
void proj_gemm(const float* __restrict__ A, const float* __restrict__ W,
               float* __restrict__ Cw, int K) {
    __shared__ float As[16][132];
    __shared__ float Bs[16][132];

    const int bm = blockIdx.x;          // M/128 tiles
    const int bn = blockIdx.y;          // N/128 tiles
    const int tid = threadIdx.x;
    const int tx = tid & 15;            // n micro
    const int ty = tid >> 4;            // m micro

    const int row0 = bm * 128;
    const int col0 = bn * 128;

    float acc[8][8];
    #pragma unroll
    for (int i = 0; i < 8; ++i)
        #pragma unroll
        for (int j = 0; j < 8; ++j) acc[i][j] = 0.f;

    for (int k0 = 0; k0 < K; k0 += 16) {
        #pragma unroll
        for (int i = 0; i < 2; ++i) {
            int f = tid + i * 256;            // float4 id 0..511
            int r = f >> 2;                   // row 0..127
            int c = (f & 3) * 4;              // k 0..12
            float4 va = *(const float4*)&A[(size_t)(row0 + r) * K + k0 + c];
            As[c + 0][r] = va.x; As[c + 1][r] = va.y;
            As[c + 2][r] = va.z; As[c + 3][r] = va.w;
            float4 vb = *(const float4*)&W[(size_t)(col0 + r) * K + k0 + c];
            Bs[c + 0][r] = vb.x; Bs[c + 1][r] = vb.y;
            Bs[c + 2][r] = vb.z; Bs[c + 3][r] = vb.w;
        }
        __syncthreads();

        #pragma unroll
        for (int kk = 0; kk < 16; ++kk) {
            float a[8], b[8];
            #pragma unroll
            for (int i = 0; i < 8; ++i) a[i] = As[kk][ty * 8 + i];
            #pragma unroll
            for (int j = 0; j < 8; ++j) b[j] = Bs[kk][tx * 8 + j];
            #pragma unroll
            for (int i = 0; i < 8; ++i)
                #pragma unroll
                for (int j = 0; j < 8; ++j)
                    acc[i][j] += a[i] * b[j];
        }
        __syncthreads();
    }

    #pragma unroll
    for (int i = 0; i < 8; ++i) {
        int m = row0 + ty * 8 + i;
        int t = m & (TLEN - 1);
        int bb = m >> 9;
        float* dst = &Cw[((size_t)t * BATCH + bb) * G2 + col0 + tx * 8];
        #pragma unroll
        for (int j = 0; j < 8; ++j) dst[j] = acc[i][j];
    }
}

// ---------------------------------------------------------------------------
// Fast grid barrier: monotonic counter, agent-scope atomics. Thread 0 of each
// WG arrives (release fence -> atomicAdd), spins with s_sleep, acquire fence,
// then __syncthreads releases the WG. grid==256 => 1 WG/CU, so thread 0's
// L1 invalidate (acquire fence) covers all threads of its WG.
// ---------------------------------------------------------------------------
__device__ __forceinline__ void grid_barrier(int* cnt, int target) {
    __syncthreads();
    if (threadIdx.x == 0) {
        __threadfence();   // release: drain stores + L2 writeback (agent scope)
        __hip_atomic_fetch_add(cnt, 1, __ATOMIC_RELAXED, __HIP_MEMORY_SCOPE_AGENT);
        while (__hip_atomic_load(cnt, __ATOMIC_RELAXED, __HIP_MEMORY_SCOPE_AGENT) < target) {
            __builtin_amdgcn_s_sleep(1);
        }
        __threadfence();   // acquire: invalidate L1/L2 so remote h is fresh
    }
    __syncthreads();
}

__global__ void rec_init(float* h0, int* cnt) {
    int i = blockIdx.x * 256 + threadIdx.x;
    if (i < BATCH * HID) h0[i] = 0.f;
    if (i == 0) *cnt = 0;
}

// ---------------------------------------------------------------------------
// Recurrence: persistent kernel, one custom barrier per timestep.
// 256 WGs x 512 threads. WG wg owns j in [wg*4, wg*4+4); keeps its 8 U rows
// (a-rows j, z-rows H+j) resident in LDS for all 512 steps.
// Thread layout: p = tid&127 -> (b = p>>2, jl = p&3); q = tid>>7 = K-quarter.
// h ping-pongs between two global buffers.
// ---------------------------------------------------------------------------
#define NWG 256
#define JPW 4

__global__ __launch_bounds__(512, 1)
void ligru_rec(const float* __restrict__ w,    // [T][B][2H]
               const float* __restrict__ U,    // [2H][H]
               float* h0w, float* h1w,         // [B][H] ping-pong
               int* __restrict__ bar,          // barrier counter (pre-zeroed)
               float* __restrict__ out,        // [B][T][H]
               float* __restrict__ hlast) {    // [B][H]
    __shared__ float Ua[JPW][HID + 4];
    __shared__ float Uz[JPW][HID + 4];
    __shared__ float red_a[3][128];
    __shared__ float red_z[3][128];

    const int wg  = blockIdx.x;
    const int tid = threadIdx.x;
    const int j0  = wg * JPW;

    // stage this WG's U slice into LDS (stays for the whole kernel)
    for (int f = tid; f < JPW * (HID / 4); f += 512) {
        int r = f / (HID / 4);
        int c = (f % (HID / 4)) * 4;
        *(float4*)&Ua[r][c] = *(const float4*)&U[(size_t)(j0 + r) * HID + c];
        *(float4*)&Uz[r][c] = *(const float4*)&U[(size_t)(HID + j0 + r) * HID + c];
    }
    __syncthreads();

    const int p  = tid & 127;
    const int q  = tid >> 7;        // K-quarter 0..3
    const int b  = p >> 2;          // 0..31
    const int jl = p & 3;           // 0..3
    const int jg = j0 + jl;
    const int k0 = q * 256;

    float* hcur = h0w;
    float* hnxt = h1w;

    for (int t = 0; t < TLEN; ++t) {
        // prefetch this step's w and previous h (used after the reduction)
        float wa = 0.f, wz = 0.f, hold = 0.f;
        if (!q) {
            const float* wt = &w[((size_t)t * BATCH + b) * G2];
            wa = wt[jg];
            wz = wt[HID + jg];
            hold = hcur[(size_t)b * HID + jg];
        }

        const float* hb = hcur + (size_t)b * HID + k0;
        const float* ua = &Ua[jl][k0];
        const float* uz = &Uz[jl][k0];
        float sa0 = 0.f, sa1 = 0.f, sz0 = 0.f, sz1 = 0.f;
        #pragma unroll 8
        for (int k = 0; k < 256; k += 8) {
            float4 hv0 = *(const float4*)&hb[k];
            float4 hv1 = *(const float4*)&hb[k + 4];
            float4 av0 = *(const float4*)&ua[k];
            float4 av1 = *(const float4*)&ua[k + 4];
            float4 zv0 = *(const float4*)&uz[k];
            float4 zv1 = *(const float4*)&uz[k + 4];
            sa0 += hv0.x * av0.x + hv0.y * av0.y + hv0.z * av0.z + hv0.w * av0.w;
            sa1 += hv1.x * av1.x + hv1.y * av1.y + hv1.z * av1.z + hv1.w * av1.w;
            sz0 += hv0.x * zv0.x + hv0.y * zv0.y + hv0.z * zv0.z + hv0.w * zv0.w;
            sz1 += hv1.x * zv1.x + hv1.y * zv1.y + hv1.z * zv1.z + hv1.w * zv1.w;
        }
        float sa = sa0 + sa1;
        float sz = sz0 + sz1;

        if (q) { red_a[q - 1][p] = sa; red_z[q - 1][p] = sz; }
        __syncthreads();
        if (!q) {
            sa += red_a[0][p] + red_a[1][p] + red_a[2][p];
            sz += red_z[0][p] + red_z[1][p] + red_z[2][p];
            float at = wa + sa;
            float zt = wz + sz;
            zt = 1.f / (1.f + expf(-zt));
            float hc = tanhf(at);
            float hnew = zt * hold + (1.f - zt) * hc;
            out[((size_t)b * TLEN + t) * HID + jg] = hnew;
            hnxt[(size_t)b * HID + jg] = hnew;
            if (t == TLEN - 1) hlast[(size_t)b * HID + jg] = hnew;
        }
        if (t < TLEN - 1) {
            grid_barrier(bar, (t + 1) * NWG);
        }
        float* tmp = hcur; hcur = hnxt; hnxt = tmp;
    }
}

// ---------------------------------------------------------------------------
extern "C" void kernel_launch(void* const* d_in, const int* in_sizes, int n_in,
                              void* d_out, int out_size, void* d_ws, size_t ws_size,
                              hipStream_t stream) {
    (void)in_sizes; (void)n_in; (void)out_size; (void)ws_size;

    const float* x  = (const float*)d_in[0];
    const float* W0 = (const float*)d_in[1];
    const float* U0 = (const float*)d_in[2];
    const float* W1 = (const float*)d_in[3];
    const float* U1 = (const float*)d_in[4];

    float* out    = (float*)d_out;                              // [B,T,H]
    float* hstack = out + (size_t)BATCH * TLEN * HID;           // [2,B,H]

    int*   bar  = (int*)d_ws;                                   // barrier counter
    float* h0   = (float*)d_ws + 16;                            // [B,H]
    float* h1   = h0 + BATCH * HID;                             // [B,H]
    float* wbuf = h1 + BATCH * HID;                             // [T][B][2H]

    dim3 gg(16384 / 128, 2048 / 128);

    // ---- layer 0 ----
    proj_gemm<<<gg, 256, 0, stream>>>(x, W0, wbuf, 512);
    rec_init<<<(BATCH * HID + 255) / 256, 256, 0, stream>>>(h0, bar);
    {
        const float* wb = wbuf; const float* Up = U0;
        float* a = h0; float* bptr = h1; int* bp = bar;
        float* o = out; float* hl = hstack;
        void* args[] = {&wb, &Up, &a, &bptr, &bp, &o, &hl};
        hipLaunchCooperativeKernel((void*)ligru_rec, dim3(NWG), dim3(512),
                                   args, 0, stream);
    }

    // ---- layer 1 ---- (reads layer-0 output staged in d_out, then overwrites it)
    proj_gemm<<<gg, 256, 0, stream>>>(out, W1, wbuf, 1024);
    rec_init<<<(BATCH * HID + 255) / 256, 256, 0, stream>>>(h0, bar);
    {
        const float* wb = wbuf; const float* Up = U1;
        float* a = h0; float* bptr = h1; int* bp = bar;
        float* o = out; float* hl = hstack + BATCH * HID;
        void* args[] = {&wb, &Up, &a, &bptr, &bp, &o, &hl};
        hipLaunchCooperativeKernel((void*)ligru_rec, dim3(NWG), dim3(512),
                                   args, 0, stream);
    }
}

// Round 3
// 26708.838 us; speedup vs baseline: 1.5263x; 1.0875x over previous
//
#include <hip/hip_runtime.h>
#include <math.h>

#define BATCH 32
#define TLEN  512
#define HID   1024
#define G2    2048   // 2*H

// ---------------------------------------------------------------------------
// Projection GEMM: Cw[t][b][n] = sum_k A[m][k] * W[n][k],  m = b*TLEN + t
// A: [M,K] row-major (M = 16384), W: [N,K] row-major (N = 2048)
// Output permuted to [T][B][2H] so the recurrence reads contiguous slabs.
// ---------------------------------------------------------------------------
__global__ __launch_bounds__(256)
void proj_gemm(const float* __restrict__ A, const float* __restrict__ W,
               float* __restrict__ Cw, int K) {
    __shared__ float As[16][132];
    __shared__ float Bs[16][132];

    const int bm = blockIdx.x;          // M/128 tiles
    const int bn = blockIdx.y;          // N/128 tiles
    const int tid = threadIdx.x;
    const int tx = tid & 15;            // n micro
    const int ty = tid >> 4;            // m micro

    const int row0 = bm * 128;
    const int col0 = bn * 128;

    float acc[8][8];
    #pragma unroll
    for (int i = 0; i < 8; ++i)
        #pragma unroll
        for (int j = 0; j < 8; ++j) acc[i][j] = 0.f;

    for (int k0 = 0; k0 < K; k0 += 16) {
        #pragma unroll
        for (int i = 0; i < 2; ++i) {
            int f = tid + i * 256;            // float4 id 0..511
            int r = f >> 2;                   // row 0..127
            int c = (f & 3) * 4;              // k 0..12
            float4 va = *(const float4*)&A[(size_t)(row0 + r) * K + k0 + c];
            As[c + 0][r] = va.x; As[c + 1][r] = va.y;
            As[c + 2][r] = va.z; As[c + 3][r] = va.w;
            float4 vb = *(const float4*)&W[(size_t)(col0 + r) * K + k0 + c];
            Bs[c + 0][r] = vb.x; Bs[c + 1][r] = vb.y;
            Bs[c + 2][r] = vb.z; Bs[c + 3][r] = vb.w;
        }
        __syncthreads();

        #pragma unroll
        for (int kk = 0; kk < 16; ++kk) {
            float a[8], b[8];
            #pragma unroll
            for (int i = 0; i < 8; ++i) a[i] = As[kk][ty * 8 + i];
            #pragma unroll
            for (int j = 0; j < 8; ++j) b[j] = Bs[kk][tx * 8 + j];
            #pragma unroll
            for (int i = 0; i < 8; ++i)
                #pragma unroll
                for (int j = 0; j < 8; ++j)
                    acc[i][j] += a[i] * b[j];
        }
        __syncthreads();
    }

    #pragma unroll
    for (int i = 0; i < 8; ++i) {
        int m = row0 + ty * 8 + i;
        int t = m & (TLEN - 1);
        int bb = m >> 9;
        float* dst = &Cw[((size_t)t * BATCH + bb) * G2 + col0 + tx * 8];
        #pragma unroll
        for (int j = 0; j < 8; ++j) dst[j] = acc[i][j];
    }
}

// ---------------------------------------------------------------------------
// Agent-scope (device-coherent) access helpers. Relaxed atomics compile to
// global_load/store with sc0 sc1 (bypass L1 + per-XCD L2, hit LLC) -- no
// cache-maintenance ops, no fences.
// ---------------------------------------------------------------------------
__device__ __forceinline__ void st_flag(int* p, int v) {
    __hip_atomic_store(p, v, __ATOMIC_RELAXED, __HIP_MEMORY_SCOPE_AGENT);
}
__device__ __forceinline__ int ld_flag(const int* p) {
    return __hip_atomic_load(p, __ATOMIC_RELAXED, __HIP_MEMORY_SCOPE_AGENT);
}
__device__ __forceinline__ void st_h(float* p, float v) {
    __hip_atomic_store(p, v, __ATOMIC_RELAXED, __HIP_MEMORY_SCOPE_AGENT);
}
__device__ __forceinline__ float ld_h(const float* p) {
    return __hip_atomic_load(p, __ATOMIC_RELAXED, __HIP_MEMORY_SCOPE_AGENT);
}
__device__ __forceinline__ uint64_t ld_h2(const float* p) {   // 8B coherent load
    return __hip_atomic_load((const uint64_t*)p, __ATOMIC_RELAXED,
                             __HIP_MEMORY_SCOPE_AGENT);
}
__device__ __forceinline__ float lo_f(uint64_t u) {
    return __uint_as_float((uint32_t)u);
}
__device__ __forceinline__ float hi_f(uint64_t u) {
    return __uint_as_float((uint32_t)(u >> 32));
}

#define NWG 256
#define JPW 4
#define FSTRIDE 32   // flags spread 128 B apart

__global__ void rec_init(float* h0, int* flags) {
    int i = blockIdx.x * 256 + threadIdx.x;
    if (i < BATCH * HID) h0[i] = 0.f;
    if (i < NWG * FSTRIDE) flags[i] = 0;
}

// ---------------------------------------------------------------------------
// Recurrence: persistent kernel. 256 WGs x 512 threads; WG wg owns j in
// [wg*4, wg*4+4), its 8 U rows live in LDS for all 512 steps.
// Thread layout: p = tid&127 -> (b = p>>2, jl = p&3); q = tid>>7 = K-quarter.
// h ping-pongs in global, accessed ONLY via agent-coherent atomics.
// Barrier: symmetric flag array, monotonic epoch, no fences, no atomic RMW.
//   Store->flag ordering: __syncthreads() drains each wave's vmcnt before
//   s_barrier (compiler-guaranteed), so all h stores are at LLC before the
//   flag store issues.
// ---------------------------------------------------------------------------
__global__ __launch_bounds__(512, 1)
void ligru_rec(const float* __restrict__ w,    // [T][B][2H]
               const float* __restrict__ U,    // [2H][H]
               float* h0w, float* h1w,         // [B][H] ping-pong
               int* __restrict__ flags,        // NWG*FSTRIDE ints, pre-zeroed
               float* __restrict__ out,        // [B][T][H]
               float* __restrict__ hlast) {    // [B][H]
    __shared__ float Ua[JPW][HID + 4];
    __shared__ float Uz[JPW][HID + 4];
    __shared__ float red_a[3][128];
    __shared__ float red_z[3][128];

    const int wg  = blockIdx.x;
    const int tid = threadIdx.x;
    const int j0  = wg * JPW;

    for (int f = tid; f < JPW * (HID / 4); f += 512) {
        int r = f / (HID / 4);
        int c = (f % (HID / 4)) * 4;
        *(float4*)&Ua[r][c] = *(const float4*)&U[(size_t)(j0 + r) * HID + c];
        *(float4*)&Uz[r][c] = *(const float4*)&U[(size_t)(HID + j0 + r) * HID + c];
    }
    __syncthreads();

    const int p  = tid & 127;
    const int q  = tid >> 7;        // K-quarter 0..3
    const int b  = p >> 2;          // 0..31
    const int jl = p & 3;           // 0..3
    const int jg = j0 + jl;
    const int k0 = q * 256;

    float* hcur = h0w;
    float* hnxt = h1w;

    for (int t = 0; t < TLEN; ++t) {
        // prefetch this step's w (plain cached loads; read-only input)
        float wa = 0.f, wz = 0.f;
        if (!q) {
            const float* wt = &w[((size_t)t * BATCH + b) * G2];
            wa = wt[jg];
            wz = wt[HID + jg];
        }

        const float* hb = hcur + (size_t)b * HID + k0;
        const float* ua = &Ua[jl][k0];
        const float* uz = &Uz[jl][k0];
        float sa0 = 0.f, sa1 = 0.f, sz0 = 0.f, sz1 = 0.f;
        #pragma unroll 8
        for (int k = 0; k < 256; k += 8) {
            uint64_t u0 = ld_h2(&hb[k]);
            uint64_t u1 = ld_h2(&hb[k + 2]);
            uint64_t u2 = ld_h2(&hb[k + 4]);
            uint64_t u3 = ld_h2(&hb[k + 6]);
            float4 av0 = *(const float4*)&ua[k];
            float4 av1 = *(const float4*)&ua[k + 4];
            float4 zv0 = *(const float4*)&uz[k];
            float4 zv1 = *(const float4*)&uz[k + 4];
            float h0f = lo_f(u0), h1f = hi_f(u0), h2f = lo_f(u1), h3f = hi_f(u1);
            float h4f = lo_f(u2), h5f = hi_f(u2), h6f = lo_f(u3), h7f = hi_f(u3);
            sa0 += h0f * av0.x + h1f * av0.y + h2f * av0.z + h3f * av0.w;
            sa1 += h4f * av1.x + h5f * av1.y + h6f * av1.z + h7f * av1.w;
            sz0 += h0f * zv0.x + h1f * zv0.y + h2f * zv0.z + h3f * zv0.w;
            sz1 += h4f * zv1.x + h5f * zv1.y + h6f * zv1.z + h7f * zv1.w;
        }
        float sa = sa0 + sa1;
        float sz = sz0 + sz1;

        if (q) { red_a[q - 1][p] = sa; red_z[q - 1][p] = sz; }
        __syncthreads();
        if (!q) {
            sa += red_a[0][p] + red_a[1][p] + red_a[2][p];
            sz += red_z[0][p] + red_z[1][p] + red_z[2][p];
            float at = wa + sa;
            float zt = wz + sz;
            zt = 1.f / (1.f + expf(-zt));
            float hc = tanhf(at);
            float hold = ld_h(&hcur[(size_t)b * HID + jg]);
            float hnew = zt * hold + (1.f - zt) * hc;
            out[((size_t)b * TLEN + t) * HID + jg] = hnew;        // plain store
            st_h(&hnxt[(size_t)b * HID + jg], hnew);              // coherent
            if (t == TLEN - 1) hlast[(size_t)b * HID + jg] = hnew;
        }

        if (t < TLEN - 1) {
            __syncthreads();   // drains vmcnt -> h stores at LLC
            if (tid == 0) st_flag(&flags[wg * FSTRIDE], t + 1);
            if (tid < NWG) {
                while (ld_flag(&flags[tid * FSTRIDE]) < t + 1)
                    __builtin_amdgcn_s_sleep(1);
            }
            __syncthreads();
        }
        float* tmp = hcur; hcur = hnxt; hnxt = tmp;
    }
}

// ---------------------------------------------------------------------------
extern "C" void kernel_launch(void* const* d_in, const int* in_sizes, int n_in,
                              void* d_out, int out_size, void* d_ws, size_t ws_size,
                              hipStream_t stream) {
    (void)in_sizes; (void)n_in; (void)out_size; (void)ws_size;

    const float* x  = (const float*)d_in[0];
    const float* W0 = (const float*)d_in[1];
    const float* U0 = (const float*)d_in[2];
    const float* W1 = (const float*)d_in[3];
    const float* U1 = (const float*)d_in[4];

    float* out    = (float*)d_out;                              // [B,T,H]
    float* hstack = out + (size_t)BATCH * TLEN * HID;           // [2,B,H]

    int*   flags = (int*)d_ws;                                  // 256*32 ints
    float* h0    = (float*)d_ws + NWG * FSTRIDE;                // [B,H]
    float* h1    = h0 + BATCH * HID;                            // [B,H]
    float* wbuf  = h1 + BATCH * HID;                            // [T][B][2H]

    dim3 gg(16384 / 128, 2048 / 128);
    int init_blocks = (BATCH * HID + NWG * FSTRIDE + 255) / 256;

    // ---- layer 0 ----
    proj_gemm<<<gg, 256, 0, stream>>>(x, W0, wbuf, 512);
    rec_init<<<init_blocks, 256, 0, stream>>>(h0, flags);
    ligru_rec<<<dim3(NWG), dim3(512), 0, stream>>>(wbuf, U0, h0, h1, flags,
                                                   out, hstack);

    // ---- layer 1 ---- (reads layer-0 output staged in d_out, then overwrites)
    proj_gemm<<<gg, 256, 0, stream>>>(out, W1, wbuf, 1024);
    rec_init<<<init_blocks, 256, 0, stream>>>(h0, flags);
    ligru_rec<<<dim3(NWG), dim3(512), 0, stream>>>(wbuf, U1, h0, h1, flags,
                                                   out, hstack + BATCH * HID);
}